// Round 1
// baseline (387.851 us; speedup 1.0000x reference)
//
#include <hip/hip_runtime.h>

#define LAMBDA_COORD 5.0f
#define LAMBDA_NOOBJ 0.5f

__global__ void zero_out_kernel(float* out) {
    out[0] = 0.0f;
}

__device__ __forceinline__ float iou_fn(float px0, float py0, float px1, float py1,
                                        float tx0, float ty0, float tx1, float ty1) {
    float ltx = fmaxf(px0, tx0);
    float lty = fmaxf(py0, ty0);
    float rbx = fminf(px1, tx1);
    float rby = fminf(py1, ty1);
    float w = fmaxf(rbx - ltx, 0.0f);
    float h = fmaxf(rby - lty, 0.0f);
    float inter = w * h;
    float a1 = (px1 - px0) * (py1 - py0);
    float a2 = (tx1 - tx0) * (ty1 - ty0);
    return inter / (a1 + a2 - inter);
}

__global__ __launch_bounds__(256) void yolo_loss_kernel(
    const float* __restrict__ pred,
    const float* __restrict__ targ,
    float* __restrict__ out,
    int ncells)
{
    int cell = blockIdx.x * blockDim.x + threadIdx.x;
    float loss = 0.0f;

    if (cell < ncells) {
        // 30 floats per cell, 120 B record -> 8-byte aligned: use float2 loads.
        const float2* p2 = (const float2*)pred + (size_t)cell * 15;
        const float2* t2 = (const float2*)targ + (size_t)cell * 15;
        float p[30], t[30];
#pragma unroll
        for (int i = 0; i < 15; ++i) {
            float2 a = p2[i];
            float2 b = t2[i];
            p[2 * i]     = a.x;
            p[2 * i + 1] = a.y;
            t[2 * i]     = b.x;
            t[2 * i + 1] = b.y;
        }

        float obj   = (t[4] > 0.0f)  ? 1.0f : 0.0f;
        float noobj = (t[4] == 0.0f) ? 1.0f : 0.0f;

        float iou0 = iou_fn(p[0], p[1], p[2], p[3], t[0], t[1], t[2], t[3]);
        float iou1 = iou_fn(p[5], p[6], p[7], p[8], t[0], t[1], t[2], t[3]);
        // jnp.argmax returns first max index -> ties pick box 0.
        bool c0 = (iou0 >= iou1);

        float l1, l2, conf;
        if (c0) {
            float dx = p[0] - t[0], dy = p[1] - t[1];
            l1 = dx * dx + dy * dy;
            float sw = sqrtf(p[2]) - sqrtf(t[2]);
            float sh = sqrtf(p[3]) - sqrtf(t[3]);
            l2 = sw * sw + sh * sh;
            float dc = p[4] - t[4];
            conf = dc * dc;
        } else {
            float dx = p[5] - t[5], dy = p[6] - t[6];
            l1 = dx * dx + dy * dy;
            float sw = sqrtf(p[7]) - sqrtf(t[7]);
            float sh = sqrtf(p[8]) - sqrtf(t[8]);
            l2 = sw * sw + sh * sh;
            float dc = p[9] - t[9];
            conf = dc * dc;
        }

        float cls = 0.0f;
#pragma unroll
        for (int c = 10; c < 30; ++c) {
            float d = p[c] - t[c];
            cls += d * d;
        }

        loss = LAMBDA_COORD * (l1 + l2) * obj
             + conf * obj
             + LAMBDA_NOOBJ * conf * noobj
             + cls * obj;
    }

    // Wave-64 reduction
#pragma unroll
    for (int off = 32; off > 0; off >>= 1)
        loss += __shfl_down(loss, off, 64);

    __shared__ float wsum[4];
    int lane = threadIdx.x & 63;
    int wid  = threadIdx.x >> 6;
    if (lane == 0) wsum[wid] = loss;
    __syncthreads();
    if (threadIdx.x == 0) {
        float s = wsum[0] + wsum[1] + wsum[2] + wsum[3];
        atomicAdd(out, s);
    }
}

extern "C" void kernel_launch(void* const* d_in, const int* in_sizes, int n_in,
                              void* d_out, int out_size, void* d_ws, size_t ws_size,
                              hipStream_t stream) {
    const float* pred = (const float*)d_in[0];
    const float* targ = (const float*)d_in[1];
    float* out = (float*)d_out;

    int ncells = in_sizes[0] / 30;  // 2048*28*28 = 1,605,632

    zero_out_kernel<<<1, 1, 0, stream>>>(out);
    int block = 256;
    int grid = (ncells + block - 1) / block;
    yolo_loss_kernel<<<grid, block, 0, stream>>>(pred, targ, out, ncells);
}